// Round 8
// baseline (637.771 us; speedup 1.0000x reference)
//
#include <hip/hip_runtime.h>

#define N_NODESC 100000
#define N_EDGESC 1600000
#define IN_DIMC 128
#define HIDC 64
#define N_GRAPHSC 512
#define PAD_DEG 64

// ---------------- setup ----------------

// zero 4 cnt replicas + compute per-graph bounds (independent work, one launch)
__global__ void zero_bounds_kernel(int* __restrict__ cntR, const int* __restrict__ batch,
                                   int* __restrict__ gstart) {
  int i = blockIdx.x * blockDim.x + threadIdx.x;
  if (i >= N_NODESC) return;
  cntR[i] = 0;
  cntR[N_NODESC + i] = 0;
  cntR[2 * N_NODESC + i] = 0;
  cntR[3 * N_NODESC + i] = 0;
  int b = batch[i];
  int prev = (i == 0) ? -1 : batch[i - 1];
  for (int g = prev + 1; g <= b; ++g) gstart[g] = i;
  if (i == N_NODESC - 1)
    for (int g = b + 1; g <= N_GRAPHSC; ++g) gstart[g] = N_NODESC;
}

// ---------------- deg + softmax-weight precompute ----------------
// deg is atomic-transaction-bound (65us, VALU 0.3%): the 512 softmax blocks
// ride free in that window (R7 measured this path adds ~nothing).
// KEEP deg SPLIT from fill (R1: fused = 150us vs 65+50) and DON'T pair
// scattered stores with streaming traffic (R7 mega3 lesson).
#define DW_DEG_B 1563
__global__ void __launch_bounds__(256)
degw_kernel(const int* __restrict__ dstv, int* __restrict__ cntR, int* __restrict__ slot,
            const float* __restrict__ closeness, const float* __restrict__ Wc,
            const float* __restrict__ bc, const int* __restrict__ gstart,
            float* __restrict__ wexp) {
  __shared__ float sArr[1024];
  __shared__ float red[256];
  int bid = blockIdx.x;
  int t = threadIdx.x;
  if (bid < DW_DEG_B) {
    int e4 = (bid * 256 + t) * 4;
    if (e4 >= N_EDGESC) return;
    int4 d = *(const int4*)(dstv + e4);
    int4 s;
    s.x = atomicAdd(&cntR[d.x], 1);
    s.y = atomicAdd(&cntR[N_NODESC + d.y], 1);
    s.z = atomicAdd(&cntR[2 * N_NODESC + d.z], 1);
    s.w = atomicAdd(&cntR[3 * N_NODESC + d.w], 1);
    *(int4*)(slot + e4) = s;
    return;
  }
  // per-graph softmax weights: wexp[n] = exp(s-smax)/ssum * count  (R0 numerics)
  int g = bid - DW_DEG_B;
  int n0 = gstart[g], n1 = gstart[g + 1];
  int count = n1 - n0;
  int cap = min(count, 1024);
  float wc0 = Wc[0], wc1 = Wc[1], wc2 = Wc[2], wc3 = Wc[3], wc4 = Wc[4], bcv = bc[0];
  float lmax = -3.4e38f;
  for (int idx = t; idx < cap; idx += 256) {
    const float* c = closeness + (size_t)(n0 + idx) * 5;
    float s = fmaf(c[4], wc4, fmaf(c[3], wc3, fmaf(c[2], wc2, fmaf(c[1], wc1, fmaf(c[0], wc0, bcv)))));
    sArr[idx] = s;
    lmax = fmaxf(lmax, s);
  }
  red[t] = lmax;
  __syncthreads();
  for (int s = 128; s > 0; s >>= 1) {
    if (t < s) red[t] = fmaxf(red[t], red[t + s]);
    __syncthreads();
  }
  float m = red[0];
  __syncthreads();
  float lsum = 0.f;
  for (int idx = t; idx < cap; idx += 256) {
    float e = expf(sArr[idx] - m);
    sArr[idx] = e;
    lsum += e;
  }
  red[t] = lsum;
  __syncthreads();
  for (int s = 128; s > 0; s >>= 1) {
    if (t < s) red[t] += red[t + s];
    __syncthreads();
  }
  float scale = (count > 0) ? ((float)count / red[0]) : 0.f;
  for (int idx = t; idx < cap; idx += 256) wexp[n0 + idx] = sArr[idx] * scale;
}

// per-node: exclusive prefix over replicas -> offR, total cnt, dinv
__global__ void off_dinv_kernel(const int* __restrict__ cntR, int* __restrict__ offR,
                                int* __restrict__ cnt, float* __restrict__ dinv) {
  int i = blockIdx.x * blockDim.x + threadIdx.x;
  if (i >= N_NODESC) return;
  int c0 = cntR[i];
  int c1 = cntR[N_NODESC + i];
  int c2 = cntR[2 * N_NODESC + i];
  int c3 = cntR[3 * N_NODESC + i];
  offR[i] = c0;
  offR[N_NODESC + i] = c0 + c1;
  offR[2 * N_NODESC + i] = c0 + c1 + c2;
  int tot = c0 + c1 + c2 + c3;
  cnt[i] = tot;
  dinv[i] = rsqrtf((float)tot + 1.0f);
}

// atomic-free padded placement: csr_pad[d*64 + offR[r][d] + slot_r[e]] = src
__global__ void fill_pad_kernel(const int* __restrict__ srcv, const int* __restrict__ dstv,
                                const int* __restrict__ slot, const int* __restrict__ offR,
                                int* __restrict__ csr_pad) {
  int e4 = (blockIdx.x * blockDim.x + threadIdx.x) * 4;
  if (e4 >= N_EDGESC) return;
  int4 s = *(const int4*)(srcv + e4);
  int4 d = *(const int4*)(dstv + e4);
  int4 sl = *(const int4*)(slot + e4);
  int p0 = sl.x;
  int p1 = offR[d.y] + sl.y;
  int p2 = offR[N_NODESC + d.z] + sl.z;
  int p3 = offR[2 * N_NODESC + d.w] + sl.w;
  if (p0 < PAD_DEG) __builtin_nontemporal_store(s.x, &csr_pad[d.x * PAD_DEG + p0]);
  if (p1 < PAD_DEG) __builtin_nontemporal_store(s.y, &csr_pad[d.y * PAD_DEG + p1]);
  if (p2 < PAD_DEG) __builtin_nontemporal_store(s.z, &csr_pad[d.z * PAD_DEG + p2]);
  if (p3 < PAD_DEG) __builtin_nontemporal_store(s.w, &csr_pad[d.w * PAD_DEG + p3]);
}

// ---------------- GCN layer GEMM: register-resident X, one row per thread ----------------
// T[row][:] = (X[row][:] @ W) * dinv[row].
//
// Why (R7 post-mortem): every LDS-staged variant (R0/R2-R5) was pinned at
// 50-68us = Little's-law bound (~8 x 16B outstanding/wave / 375ns x 12
// waves/CU ~= 1 TB/s, matching every measurement).  Here each thread issues
// its ENTIRE X row as 16-32 dwordx4 loads (256-512B/lane in flight, 16-32x
// deeper), W is LDS-staged once and read via same-address broadcast (no
// conflicts by definition), and the K-loop has ZERO barriers.
//  - grid 782 x 128thr (2 waves): ~3 blocks/CU balanced.
//  - acc = 16 cols at a time (cb-loop, unroll 1: keeps I-footprint ~10-20KB
//    and VGPR ~= KT + 16 + tmp -> 110 (K=64) / 190 (K=128)).
//  - k-loop fully unrolled: xr[] indexed by compile-time constants only
//    (runtime-indexed reg arrays spill to scratch).
#define GR_BLOCKS ((N_NODESC + 127) / 128)  // 782

template <int KT>
__global__ void __launch_bounds__(128)
gemm_row_kernel(const float* __restrict__ X, const float* __restrict__ W,
                const float* __restrict__ dinv, float* __restrict__ T) {
  __shared__ float ws[KT * HIDC];
  int t = threadIdx.x;
  int row = blockIdx.x * 128 + t;
  int r = (row < N_NODESC) ? row : (N_NODESC - 1);

  // issue the full X row into regs FIRST: latency hides under W staging+barrier
  float4 xr[KT / 4];
#pragma unroll
  for (int i = 0; i < KT / 4; ++i)
    xr[i] = *(const float4*)(X + (size_t)r * KT + i * 4);

  // stage W coalesced (16B/lane contiguous)
#pragma unroll
  for (int f = t; f < KT * HIDC / 4; f += 128)
    *(float4*)(ws + (size_t)f * 4) = *(const float4*)(W + (size_t)f * 4);
  __syncthreads();

  float dv = dinv[r];
  bool valid = row < N_NODESC;
  float* orow = T + (size_t)r * HIDC;

#pragma unroll 1
  for (int cb = 0; cb < 4; ++cb) {
    const float* wp = ws + cb * 16;
    float4 a0 = make_float4(0.f, 0.f, 0.f, 0.f);
    float4 a1 = a0, a2 = a0, a3 = a0;
#pragma unroll
    for (int k = 0; k < KT; ++k) {
      const float4 q = xr[k >> 2];
      const float xv = ((k & 3) == 0) ? q.x : ((k & 3) == 1) ? q.y : ((k & 3) == 2) ? q.z : q.w;
      float4 w0 = *(const float4*)(wp + k * HIDC);
      float4 w1 = *(const float4*)(wp + k * HIDC + 4);
      float4 w2 = *(const float4*)(wp + k * HIDC + 8);
      float4 w3 = *(const float4*)(wp + k * HIDC + 12);
      a0.x = fmaf(xv, w0.x, a0.x);
      a0.y = fmaf(xv, w0.y, a0.y);
      a0.z = fmaf(xv, w0.z, a0.z);
      a0.w = fmaf(xv, w0.w, a0.w);
      a1.x = fmaf(xv, w1.x, a1.x);
      a1.y = fmaf(xv, w1.y, a1.y);
      a1.z = fmaf(xv, w1.z, a1.z);
      a1.w = fmaf(xv, w1.w, a1.w);
      a2.x = fmaf(xv, w2.x, a2.x);
      a2.y = fmaf(xv, w2.y, a2.y);
      a2.z = fmaf(xv, w2.z, a2.z);
      a2.w = fmaf(xv, w2.w, a2.w);
      a3.x = fmaf(xv, w3.x, a3.x);
      a3.y = fmaf(xv, w3.y, a3.y);
      a3.z = fmaf(xv, w3.z, a3.z);
      a3.w = fmaf(xv, w3.w, a3.w);
    }
    if (valid) {
      float4 o0, o1, o2, o3;
      o0.x = a0.x * dv; o0.y = a0.y * dv; o0.z = a0.z * dv; o0.w = a0.w * dv;
      o1.x = a1.x * dv; o1.y = a1.y * dv; o1.z = a1.z * dv; o1.w = a1.w * dv;
      o2.x = a2.x * dv; o2.y = a2.y * dv; o2.z = a2.z * dv; o2.w = a2.w * dv;
      o3.x = a3.x * dv; o3.y = a3.y * dv; o3.z = a3.z * dv; o3.w = a3.w * dv;
      *(float4*)(orow + cb * 16 + 0) = o0;
      *(float4*)(orow + cb * 16 + 4) = o1;
      *(float4*)(orow + cb * 16 + 8) = o2;
      *(float4*)(orow + cb * 16 + 12) = o3;
    }
  }
}

// h[i][:] = relu(dinv[i]*(ts[i][:] + sum_{s in pad-row i} ts[s][:]) + b)
// (unchanged R0-proven kernel)
__global__ void gather_kernel(const float* __restrict__ ts, const float* __restrict__ dinv,
                              const int* __restrict__ cnt, const int* __restrict__ csr_pad,
                              const float* __restrict__ bias, float* __restrict__ h) {
  int lane = threadIdx.x & 63;
  int node = (blockIdx.x * blockDim.x + threadIdx.x) >> 6;
  if (node >= N_NODESC) return;
  int q = lane >> 4;
  int c = lane & 15;
  int deg = min(cnt[node], PAD_DEG);
  const int* __restrict__ row = csr_pad + node * PAD_DEG;
  const float4* __restrict__ ts4 = (const float4*)ts;
  float4 acc = make_float4(0.f, 0.f, 0.f, 0.f);
  int e = 0;
  for (; e + 16 <= deg; e += 16) {
    int s0 = row[e + q];
    int s1 = row[e + 4 + q];
    int s2 = row[e + 8 + q];
    int s3 = row[e + 12 + q];
    float4 v0 = ts4[s0 * 16 + c];
    float4 v1 = ts4[s1 * 16 + c];
    float4 v2 = ts4[s2 * 16 + c];
    float4 v3 = ts4[s3 * 16 + c];
    acc.x += (v0.x + v1.x) + (v2.x + v3.x);
    acc.y += (v0.y + v1.y) + (v2.y + v3.y);
    acc.z += (v0.z + v1.z) + (v2.z + v3.z);
    acc.w += (v0.w + v1.w) + (v2.w + v3.w);
  }
  for (; e + 4 <= deg; e += 4) {
    int s0 = row[e + q];
    float4 v = ts4[s0 * 16 + c];
    acc.x += v.x;
    acc.y += v.y;
    acc.z += v.z;
    acc.w += v.w;
  }
  if (e < deg && q < deg - e) {
    int s0 = row[e + q];
    float4 v = ts4[s0 * 16 + c];
    acc.x += v.x;
    acc.y += v.y;
    acc.z += v.z;
    acc.w += v.w;
  }
  acc.x += __shfl_xor(acc.x, 16);
  acc.y += __shfl_xor(acc.y, 16);
  acc.z += __shfl_xor(acc.z, 16);
  acc.w += __shfl_xor(acc.w, 16);
  acc.x += __shfl_xor(acc.x, 32);
  acc.y += __shfl_xor(acc.y, 32);
  acc.z += __shfl_xor(acc.z, 32);
  acc.w += __shfl_xor(acc.w, 32);
  if (q == 0) {
    float4 self = ts4[node * 16 + c];
    float4 bv = ((const float4*)bias)[c];
    float dv = dinv[node];
    float4 o;
    o.x = fmaxf(fmaf(acc.x + self.x, dv, bv.x), 0.f);
    o.y = fmaxf(fmaf(acc.y + self.y, dv, bv.y), 0.f);
    o.z = fmaxf(fmaf(acc.z + self.z, dv, bv.z), 0.f);
    o.w = fmaxf(fmaf(acc.w + self.w, dv, bv.w), 0.f);
    ((float4*)h)[node * 16 + c] = o;
  }
}

// ---------------- slim readout: weighted max-pool + MLP (weights precomputed) ----------------
__global__ void __launch_bounds__(256)
readout2_kernel(const float* __restrict__ h, const float* __restrict__ wexp,
                const int* __restrict__ gstart, const float* __restrict__ Wa1,
                const float* __restrict__ ba1, const float* __restrict__ Wa2,
                const float* __restrict__ ba2, float* __restrict__ out) {
  __shared__ float cross[4 * 64];
  int g = blockIdx.x;
  int t = threadIdx.x;
  int n0 = gstart[g], n1 = gstart[g + 1];
  int cap = min(n1 - n0, 1024);
  int wv = t >> 6, lane = t & 63;
  float pmax = 0.f;  // values nonneg (relu * positive weight)
  for (int idx = wv; idx < cap; idx += 4) {
    pmax = fmaxf(pmax, wexp[n0 + idx] * h[(size_t)(n0 + idx) * HIDC + lane]);
  }
  cross[wv * 64 + lane] = pmax;
  __syncthreads();
  if (wv == 0) {
    float p = fmaxf(fmaxf(cross[lane], cross[64 + lane]),
                    fmaxf(cross[128 + lane], cross[192 + lane]));
    float o = 0.f;
#pragma unroll
    for (int tt = 0; tt < 16; ++tt) {
      float prod = p * Wa1[lane * 16 + tt];
#pragma unroll
      for (int off = 32; off > 0; off >>= 1) prod += __shfl_xor(prod, off);
      float a = fmaxf(prod + ba1[tt], 0.f);
      o += a * Wa2[tt];
    }
    if (lane == 0) out[g] = o + ba2[0];
  }
}

// ---------------- launch ----------------

extern "C" void kernel_launch(void* const* d_in, const int* in_sizes, int n_in,
                              void* d_out, int out_size, void* d_ws, size_t ws_size,
                              hipStream_t stream) {
  const float* x = (const float*)d_in[0];
  const int* ei = (const int*)d_in[1];
  const float* closeness = (const float*)d_in[2];
  const int* batch = (const int*)d_in[3];
  const float* W1 = (const float*)d_in[5];
  const float* b1 = (const float*)d_in[6];
  const float* W2 = (const float*)d_in[7];
  const float* b2 = (const float*)d_in[8];
  const float* W3 = (const float*)d_in[9];
  const float* b3 = (const float*)d_in[10];
  const float* Wc = (const float*)d_in[11];
  const float* bc = (const float*)d_in[12];
  const float* Wa1 = (const float*)d_in[13];
  const float* ba1 = (const float*)d_in[14];
  const float* Wa2 = (const float*)d_in[15];
  const float* ba2 = (const float*)d_in[16];
  float* out = (float*)d_out;
  const int* srcv = ei;
  const int* dstv = ei + N_EDGESC;

  char* ws = (char*)d_ws;
  size_t off = 0;
  auto alloc = [&](size_t bytes) -> void* {
    void* p = ws + off;
    off = (off + bytes + 255) & ~(size_t)255;
    return p;
  };
  float* tbuf = (float*)alloc(sizeof(float) * N_NODESC * HIDC);   // 25.6 MB
  float* hbuf = (float*)alloc(sizeof(float) * N_NODESC * HIDC);   // 25.6 MB
  int* csr_pad = (int*)alloc(sizeof(int) * N_NODESC * PAD_DEG);   // 25.6 MB
  int* slot = (int*)alloc(sizeof(int) * N_EDGESC);                // 6.4 MB
  int* cntR = (int*)alloc(sizeof(int) * N_NODESC * 4);            // 1.6 MB
  int* offR = (int*)alloc(sizeof(int) * N_NODESC * 3);            // 1.2 MB
  int* cnt = (int*)alloc(sizeof(int) * N_NODESC);
  float* dinv = (float*)alloc(sizeof(float) * N_NODESC);
  float* wexp = (float*)alloc(sizeof(float) * N_NODESC);
  int* gstart = (int*)alloc(sizeof(int) * (N_GRAPHSC + 1));

  const int B = 256;
  int gN = (N_NODESC + B - 1) / B;           // 391
  int gE4 = (N_EDGESC / 4 + B - 1) / B;      // 1563
  int gGather = (N_NODESC * 64) / B;         // 25000

  zero_bounds_kernel<<<gN, B, 0, stream>>>(cntR, batch, gstart);
  // deg (atomic-bound) + softmax-weight blocks riding free
  degw_kernel<<<DW_DEG_B + N_GRAPHSC, B, 0, stream>>>(dstv, cntR, slot,
                                                      closeness, Wc, bc, gstart, wexp);
  off_dinv_kernel<<<gN, B, 0, stream>>>(cntR, offR, cnt, dinv);
  // layer-1 GEMM (needs dinv) then fill
  gemm_row_kernel<IN_DIMC><<<GR_BLOCKS, 128, 0, stream>>>(x, W1, dinv, tbuf);
  fill_pad_kernel<<<gE4, B, 0, stream>>>(srcv, dstv, slot, offR, csr_pad);

  // layer 1 aggregate
  gather_kernel<<<gGather, B, 0, stream>>>(tbuf, dinv, cnt, csr_pad, b1, hbuf);
  // layer 2
  gemm_row_kernel<HIDC><<<GR_BLOCKS, 128, 0, stream>>>(hbuf, W2, dinv, tbuf);
  gather_kernel<<<gGather, B, 0, stream>>>(tbuf, dinv, cnt, csr_pad, b2, hbuf);
  // layer 3
  gemm_row_kernel<HIDC><<<GR_BLOCKS, 128, 0, stream>>>(hbuf, W3, dinv, tbuf);
  gather_kernel<<<gGather, B, 0, stream>>>(tbuf, dinv, cnt, csr_pad, b3, hbuf);

  // slim readout
  readout2_kernel<<<N_GRAPHSC, B, 0, stream>>>(hbuf, wexp, gstart, Wa1, ba1, Wa2, ba2, out);
}

// Round 10
// 548.646 us; speedup vs baseline: 1.1624x; 1.1624x over previous
//
#include <hip/hip_runtime.h>

#define N_NODESC 100000
#define N_EDGESC 1600000
#define IN_DIMC 128
#define HIDC 64
#define N_GRAPHSC 512
#define PAD_DEG 64

// ---------------- setup ----------------

// zero 4 cnt replicas + compute per-graph bounds (independent work, one launch)
__global__ void zero_bounds_kernel(int* __restrict__ cntR, const int* __restrict__ batch,
                                   int* __restrict__ gstart) {
  int i = blockIdx.x * blockDim.x + threadIdx.x;
  if (i >= N_NODESC) return;
  cntR[i] = 0;
  cntR[N_NODESC + i] = 0;
  cntR[2 * N_NODESC + i] = 0;
  cntR[3 * N_NODESC + i] = 0;
  int b = batch[i];
  int prev = (i == 0) ? -1 : batch[i - 1];
  for (int g = prev + 1; g <= b; ++g) gstart[g] = i;
  if (i == N_NODESC - 1)
    for (int g = b + 1; g <= N_GRAPHSC; ++g) gstart[g] = N_NODESC;
}

// ---------------- deg + softmax-weight precompute (R8-verified) ----------------
// deg is atomic-transaction-bound (65us, VALU 0.3%): the 512 softmax blocks
// ride free in that window.  KEEP deg SPLIT from fill (R1: fused = 150us)
// and DON'T pair scattered stores with streaming traffic (R7 mega3 lesson).
#define DW_DEG_B 1563
__global__ void __launch_bounds__(256)
degw_kernel(const int* __restrict__ dstv, int* __restrict__ cntR, int* __restrict__ slot,
            const float* __restrict__ closeness, const float* __restrict__ Wc,
            const float* __restrict__ bc, const int* __restrict__ gstart,
            float* __restrict__ wexp) {
  __shared__ float sArr[1024];
  __shared__ float red[256];
  int bid = blockIdx.x;
  int t = threadIdx.x;
  if (bid < DW_DEG_B) {
    int e4 = (bid * 256 + t) * 4;
    if (e4 >= N_EDGESC) return;
    int4 d = *(const int4*)(dstv + e4);
    int4 s;
    s.x = atomicAdd(&cntR[d.x], 1);
    s.y = atomicAdd(&cntR[N_NODESC + d.y], 1);
    s.z = atomicAdd(&cntR[2 * N_NODESC + d.z], 1);
    s.w = atomicAdd(&cntR[3 * N_NODESC + d.w], 1);
    *(int4*)(slot + e4) = s;
    return;
  }
  // per-graph softmax weights: wexp[n] = exp(s-smax)/ssum * count  (R0 numerics)
  int g = bid - DW_DEG_B;
  int n0 = gstart[g], n1 = gstart[g + 1];
  int count = n1 - n0;
  int cap = min(count, 1024);
  float wc0 = Wc[0], wc1 = Wc[1], wc2 = Wc[2], wc3 = Wc[3], wc4 = Wc[4], bcv = bc[0];
  float lmax = -3.4e38f;
  for (int idx = t; idx < cap; idx += 256) {
    const float* c = closeness + (size_t)(n0 + idx) * 5;
    float s = fmaf(c[4], wc4, fmaf(c[3], wc3, fmaf(c[2], wc2, fmaf(c[1], wc1, fmaf(c[0], wc0, bcv)))));
    sArr[idx] = s;
    lmax = fmaxf(lmax, s);
  }
  red[t] = lmax;
  __syncthreads();
  for (int s = 128; s > 0; s >>= 1) {
    if (t < s) red[t] = fmaxf(red[t], red[t + s]);
    __syncthreads();
  }
  float m = red[0];
  __syncthreads();
  float lsum = 0.f;
  for (int idx = t; idx < cap; idx += 256) {
    float e = expf(sArr[idx] - m);
    sArr[idx] = e;
    lsum += e;
  }
  red[t] = lsum;
  __syncthreads();
  for (int s = 128; s > 0; s >>= 1) {
    if (t < s) red[t] += red[t + s];
    __syncthreads();
  }
  float scale = (count > 0) ? ((float)count / red[0]) : 0.f;
  for (int idx = t; idx < cap; idx += 256) wexp[n0 + idx] = sArr[idx] * scale;
}

// per-node: exclusive prefix over replicas -> offR, total cnt, dinv
__global__ void off_dinv_kernel(const int* __restrict__ cntR, int* __restrict__ offR,
                                int* __restrict__ cnt, float* __restrict__ dinv) {
  int i = blockIdx.x * blockDim.x + threadIdx.x;
  if (i >= N_NODESC) return;
  int c0 = cntR[i];
  int c1 = cntR[N_NODESC + i];
  int c2 = cntR[2 * N_NODESC + i];
  int c3 = cntR[3 * N_NODESC + i];
  offR[i] = c0;
  offR[N_NODESC + i] = c0 + c1;
  offR[2 * N_NODESC + i] = c0 + c1 + c2;
  int tot = c0 + c1 + c2 + c3;
  cnt[i] = tot;
  dinv[i] = rsqrtf((float)tot + 1.0f);
}

// atomic-free padded placement: csr_pad[d*64 + offR[r][d] + slot_r[e]] = src
__global__ void fill_pad_kernel(const int* __restrict__ srcv, const int* __restrict__ dstv,
                                const int* __restrict__ slot, const int* __restrict__ offR,
                                int* __restrict__ csr_pad) {
  int e4 = (blockIdx.x * blockDim.x + threadIdx.x) * 4;
  if (e4 >= N_EDGESC) return;
  int4 s = *(const int4*)(srcv + e4);
  int4 d = *(const int4*)(dstv + e4);
  int4 sl = *(const int4*)(slot + e4);
  int p0 = sl.x;
  int p1 = offR[d.y] + sl.y;
  int p2 = offR[N_NODESC + d.z] + sl.z;
  int p3 = offR[2 * N_NODESC + d.w] + sl.w;
  if (p0 < PAD_DEG) __builtin_nontemporal_store(s.x, &csr_pad[d.x * PAD_DEG + p0]);
  if (p1 < PAD_DEG) __builtin_nontemporal_store(s.y, &csr_pad[d.y * PAD_DEG + p1]);
  if (p2 < PAD_DEG) __builtin_nontemporal_store(s.z, &csr_pad[d.z * PAD_DEG + p2]);
  if (p3 < PAD_DEG) __builtin_nontemporal_store(s.w, &csr_pad[d.w * PAD_DEG + p3]);
}

// ---------------- GCN layer GEMM: row-per-lane + W LDS broadcast ----------------
// T[row][:] = (X[row][:] @ W) * dinv[row].
//
// R8 post-mortem fixes, all three at once:
//  - row CHUNKED in regs (4+4 float4 double-buffer = 32 VGPR, not 128):
//    prefetch chunk c+1 issued before computing chunk c (~512B/lane in
//    flight; 2048 cyc of FMA per chunk hides the ~900cyc HBM latency).
//  - all 64 output cols accumulated per lane (16 float4 = 64 VGPR, static
//    indexing only).  Total VGPR ~130 -> 3 waves/SIMD (R8 was 256 VGPR).
//  - W read per k at a UNIFORM address (same W row for every lane) ->
//    hardware broadcast, no bank conflicts, only 16 ds_read_b128 per
//    64 v_fmac.  ZERO barriers in the K-loop (W staged once up front).
//  - 782 blocks x 128thr = 3.05 blocks/CU balanced; 1563 row-waves.
#define GB_BLOCKS ((N_NODESC + 127) / 128)  // 782

template <int KT>
__global__ void __launch_bounds__(128)
gemm_bcast_kernel(const float* __restrict__ X, const float* __restrict__ W,
                  const float* __restrict__ dinv, float* __restrict__ T) {
  __shared__ float ws[KT * HIDC];  // 16KB (K=64) / 32KB (K=128)
  int t = threadIdx.x;
  int row = blockIdx.x * 128 + t;
  int r = (row < N_NODESC) ? row : (N_NODESC - 1);
  const float* __restrict__ xrow = X + (size_t)r * KT;

  // issue first chunk loads before W staging so they overlap it
  float4 xa0 = *(const float4*)(xrow + 0);
  float4 xa1 = *(const float4*)(xrow + 4);
  float4 xa2 = *(const float4*)(xrow + 8);
  float4 xa3 = *(const float4*)(xrow + 12);

  // stage W coalesced: KT*16 float4 / 128 threads
#pragma unroll
  for (int f = t; f < KT * HIDC / 4; f += 128)
    ((float4*)ws)[f] = ((const float4*)W)[f];
  __syncthreads();

  float4 acc[16];
#pragma unroll
  for (int j = 0; j < 16; ++j) acc[j] = make_float4(0.f, 0.f, 0.f, 0.f);

  constexpr int NCH = KT / 16;
  float4 xb0, xb1, xb2, xb3;
#pragma unroll 1
  for (int c = 0; c < NCH; ++c) {
    if (c + 1 < NCH) {  // prefetch next chunk (waits only at the copy below)
      const float* nx = xrow + (c + 1) * 16;
      xb0 = *(const float4*)(nx + 0);
      xb1 = *(const float4*)(nx + 4);
      xb2 = *(const float4*)(nx + 8);
      xb3 = *(const float4*)(nx + 12);
    }
    const float* wbase = ws + c * 16 * HIDC;
#pragma unroll
    for (int k = 0; k < 16; ++k) {
      const float4 q = (k < 4) ? xa0 : (k < 8) ? xa1 : (k < 12) ? xa2 : xa3;
      const float xv = ((k & 3) == 0) ? q.x : ((k & 3) == 1) ? q.y : ((k & 3) == 2) ? q.z : q.w;
      const float4* wrow = (const float4*)(wbase + k * HIDC);  // uniform addr -> broadcast
#pragma unroll
      for (int j = 0; j < 16; ++j) {
        float4 w = wrow[j];
        acc[j].x = fmaf(xv, w.x, acc[j].x);
        acc[j].y = fmaf(xv, w.y, acc[j].y);
        acc[j].z = fmaf(xv, w.z, acc[j].z);
        acc[j].w = fmaf(xv, w.w, acc[j].w);
      }
    }
    xa0 = xb0; xa1 = xb1; xa2 = xb2; xa3 = xb3;
  }

  if (row < N_NODESC) {
    float dv = dinv[r];
    float4* orow = (float4*)(T + (size_t)r * HIDC);
#pragma unroll
    for (int j = 0; j < 16; ++j) {
      float4 o;
      o.x = acc[j].x * dv;
      o.y = acc[j].y * dv;
      o.z = acc[j].z * dv;
      o.w = acc[j].w * dv;
      orow[j] = o;
    }
  }
}

// h[i][:] = relu(dinv[i]*(ts[i][:] + sum_{s in pad-row i} ts[s][:]) + b)
// (unchanged R0-proven kernel)
__global__ void gather_kernel(const float* __restrict__ ts, const float* __restrict__ dinv,
                              const int* __restrict__ cnt, const int* __restrict__ csr_pad,
                              const float* __restrict__ bias, float* __restrict__ h) {
  int lane = threadIdx.x & 63;
  int node = (blockIdx.x * blockDim.x + threadIdx.x) >> 6;
  if (node >= N_NODESC) return;
  int q = lane >> 4;
  int c = lane & 15;
  int deg = min(cnt[node], PAD_DEG);
  const int* __restrict__ row = csr_pad + node * PAD_DEG;
  const float4* __restrict__ ts4 = (const float4*)ts;
  float4 acc = make_float4(0.f, 0.f, 0.f, 0.f);
  int e = 0;
  for (; e + 16 <= deg; e += 16) {
    int s0 = row[e + q];
    int s1 = row[e + 4 + q];
    int s2 = row[e + 8 + q];
    int s3 = row[e + 12 + q];
    float4 v0 = ts4[s0 * 16 + c];
    float4 v1 = ts4[s1 * 16 + c];
    float4 v2 = ts4[s2 * 16 + c];
    float4 v3 = ts4[s3 * 16 + c];
    acc.x += (v0.x + v1.x) + (v2.x + v3.x);
    acc.y += (v0.y + v1.y) + (v2.y + v3.y);
    acc.z += (v0.z + v1.z) + (v2.z + v3.z);
    acc.w += (v0.w + v1.w) + (v2.w + v3.w);
  }
  for (; e + 4 <= deg; e += 4) {
    int s0 = row[e + q];
    float4 v = ts4[s0 * 16 + c];
    acc.x += v.x;
    acc.y += v.y;
    acc.z += v.z;
    acc.w += v.w;
  }
  if (e < deg && q < deg - e) {
    int s0 = row[e + q];
    float4 v = ts4[s0 * 16 + c];
    acc.x += v.x;
    acc.y += v.y;
    acc.z += v.z;
    acc.w += v.w;
  }
  acc.x += __shfl_xor(acc.x, 16);
  acc.y += __shfl_xor(acc.y, 16);
  acc.z += __shfl_xor(acc.z, 16);
  acc.w += __shfl_xor(acc.w, 16);
  acc.x += __shfl_xor(acc.x, 32);
  acc.y += __shfl_xor(acc.y, 32);
  acc.z += __shfl_xor(acc.z, 32);
  acc.w += __shfl_xor(acc.w, 32);
  if (q == 0) {
    float4 self = ts4[node * 16 + c];
    float4 bv = ((const float4*)bias)[c];
    float dv = dinv[node];
    float4 o;
    o.x = fmaxf(fmaf(acc.x + self.x, dv, bv.x), 0.f);
    o.y = fmaxf(fmaf(acc.y + self.y, dv, bv.y), 0.f);
    o.z = fmaxf(fmaf(acc.z + self.z, dv, bv.z), 0.f);
    o.w = fmaxf(fmaf(acc.w + self.w, dv, bv.w), 0.f);
    ((float4*)h)[node * 16 + c] = o;
  }
}

// ---------------- slim readout: weighted max-pool + MLP (weights precomputed) ----------------
__global__ void __launch_bounds__(256)
readout2_kernel(const float* __restrict__ h, const float* __restrict__ wexp,
                const int* __restrict__ gstart, const float* __restrict__ Wa1,
                const float* __restrict__ ba1, const float* __restrict__ Wa2,
                const float* __restrict__ ba2, float* __restrict__ out) {
  __shared__ float cross[4 * 64];
  int g = blockIdx.x;
  int t = threadIdx.x;
  int n0 = gstart[g], n1 = gstart[g + 1];
  int cap = min(n1 - n0, 1024);
  int wv = t >> 6, lane = t & 63;
  float pmax = 0.f;  // values nonneg (relu * positive weight)
  for (int idx = wv; idx < cap; idx += 4) {
    pmax = fmaxf(pmax, wexp[n0 + idx] * h[(size_t)(n0 + idx) * HIDC + lane]);
  }
  cross[wv * 64 + lane] = pmax;
  __syncthreads();
  if (wv == 0) {
    float p = fmaxf(fmaxf(cross[lane], cross[64 + lane]),
                    fmaxf(cross[128 + lane], cross[192 + lane]));
    float o = 0.f;
#pragma unroll
    for (int tt = 0; tt < 16; ++tt) {
      float prod = p * Wa1[lane * 16 + tt];
#pragma unroll
      for (int off = 32; off > 0; off >>= 1) prod += __shfl_xor(prod, off);
      float a = fmaxf(prod + ba1[tt], 0.f);
      o += a * Wa2[tt];
    }
    if (lane == 0) out[g] = o + ba2[0];
  }
}

// ---------------- launch ----------------

extern "C" void kernel_launch(void* const* d_in, const int* in_sizes, int n_in,
                              void* d_out, int out_size, void* d_ws, size_t ws_size,
                              hipStream_t stream) {
  const float* x = (const float*)d_in[0];
  const int* ei = (const int*)d_in[1];
  const float* closeness = (const float*)d_in[2];
  const int* batch = (const int*)d_in[3];
  const float* W1 = (const float*)d_in[5];
  const float* b1 = (const float*)d_in[6];
  const float* W2 = (const float*)d_in[7];
  const float* b2 = (const float*)d_in[8];
  const float* W3 = (const float*)d_in[9];
  const float* b3 = (const float*)d_in[10];
  const float* Wc = (const float*)d_in[11];
  const float* bc = (const float*)d_in[12];
  const float* Wa1 = (const float*)d_in[13];
  const float* ba1 = (const float*)d_in[14];
  const float* Wa2 = (const float*)d_in[15];
  const float* ba2 = (const float*)d_in[16];
  float* out = (float*)d_out;
  const int* srcv = ei;
  const int* dstv = ei + N_EDGESC;

  char* ws = (char*)d_ws;
  size_t off = 0;
  auto alloc = [&](size_t bytes) -> void* {
    void* p = ws + off;
    off = (off + bytes + 255) & ~(size_t)255;
    return p;
  };
  float* tbuf = (float*)alloc(sizeof(float) * N_NODESC * HIDC);   // 25.6 MB
  float* hbuf = (float*)alloc(sizeof(float) * N_NODESC * HIDC);   // 25.6 MB
  int* csr_pad = (int*)alloc(sizeof(int) * N_NODESC * PAD_DEG);   // 25.6 MB
  int* slot = (int*)alloc(sizeof(int) * N_EDGESC);                // 6.4 MB
  int* cntR = (int*)alloc(sizeof(int) * N_NODESC * 4);            // 1.6 MB
  int* offR = (int*)alloc(sizeof(int) * N_NODESC * 3);            // 1.2 MB
  int* cnt = (int*)alloc(sizeof(int) * N_NODESC);
  float* dinv = (float*)alloc(sizeof(float) * N_NODESC);
  float* wexp = (float*)alloc(sizeof(float) * N_NODESC);
  int* gstart = (int*)alloc(sizeof(int) * (N_GRAPHSC + 1));

  const int B = 256;
  int gN = (N_NODESC + B - 1) / B;           // 391
  int gE4 = (N_EDGESC / 4 + B - 1) / B;      // 1563
  int gGather = (N_NODESC * 64) / B;         // 25000

  zero_bounds_kernel<<<gN, B, 0, stream>>>(cntR, batch, gstart);
  // deg (atomic-bound) + softmax-weight blocks riding free
  degw_kernel<<<DW_DEG_B + N_GRAPHSC, B, 0, stream>>>(dstv, cntR, slot,
                                                      closeness, Wc, bc, gstart, wexp);
  off_dinv_kernel<<<gN, B, 0, stream>>>(cntR, offR, cnt, dinv);
  // layer-1 GEMM (needs dinv) then fill
  gemm_bcast_kernel<IN_DIMC><<<GB_BLOCKS, 128, 0, stream>>>(x, W1, dinv, tbuf);
  fill_pad_kernel<<<gE4, B, 0, stream>>>(srcv, dstv, slot, offR, csr_pad);

  // layer 1 aggregate
  gather_kernel<<<gGather, B, 0, stream>>>(tbuf, dinv, cnt, csr_pad, b1, hbuf);
  // layer 2
  gemm_bcast_kernel<HIDC><<<GB_BLOCKS, 128, 0, stream>>>(hbuf, W2, dinv, tbuf);
  gather_kernel<<<gGather, B, 0, stream>>>(tbuf, dinv, cnt, csr_pad, b2, hbuf);
  // layer 3
  gemm_bcast_kernel<HIDC><<<GB_BLOCKS, 128, 0, stream>>>(hbuf, W3, dinv, tbuf);
  gather_kernel<<<gGather, B, 0, stream>>>(tbuf, dinv, cnt, csr_pad, b3, hbuf);

  // slim readout
  readout2_kernel<<<N_GRAPHSC, B, 0, stream>>>(hbuf, wexp, gstart, Wa1, ba1, Wa2, ba2, out);
}